// Round 6
// baseline (144.880 us; speedup 1.0000x reference)
//
#include <hip/hip_runtime.h>
#include <hip/hip_bf16.h>
#include <cstdint>
#include <cstddef>

// Shapes (fixed): B=8, LB=512, LC=128, H=256, H2=512, MIN_WS=5, N_WIN=4
// Windows: ws=5,10,15,20 ; n_seg=102,101,100,99 ; total 402
// d_out: out[8*256] | s_score[8*402] | b_score[8*512]  (floats)

typedef unsigned short ushort8 __attribute__((ext_vector_type(8)));
typedef float f32x4 __attribute__((ext_vector_type(4)));

__device__ __forceinline__ float fsigmoid(float x) { return 1.0f / (1.0f + __expf(-x)); }
__device__ __forceinline__ float ftanh(float x) {
  float e = __expf(2.0f * x);
  return 1.0f - 2.0f / (e + 1.0f);
}
__device__ __forceinline__ unsigned short f2bf(float x) {
  union { float f; unsigned u; } v; v.f = x;
  unsigned r = (v.u + 0x7FFFu + ((v.u >> 16) & 1u)) >> 16;
  return (unsigned short)r;
}
__device__ __forceinline__ f32x4 mfma_bf16(ushort8 a, ushort8 b, f32x4 c) {
  asm("v_mfma_f32_16x16x32_bf16 %0, %1, %2, %0" : "+v"(c) : "v"(a), "v"(b));
  return c;
}

// ---------------- prep: weight transpose/convert + concats + wqa ---------------
struct WArg { const float* s[15]; };
__global__ __launch_bounds__(256) void prep_k(WArg wa, unsigned short* __restrict__ WT,
    const float* __restrict__ benc, const float* __restrict__ cenc,
    const float* __restrict__ cs,
    unsigned short* __restrict__ XB0, unsigned short* __restrict__ XC0,
    const float* __restrict__ aWq, const float* __restrict__ abq,
    float* __restrict__ wqa) {
  __shared__ float tile[64][65];
  const int blk = blockIdx.x, t = threadIdx.x;
  if (blk < 960) {
    const int mat = blk >> 6, q = blk & 63;
    const int Kd = (mat == 14) ? 256 : 512;
    const int k0 = (q >> 3) << 6, n0 = (q & 7) << 6;
    if (mat == 14 && (k0 >= 256 || n0 >= 256)) return;
    const float* __restrict__ S = wa.s[mat];
    unsigned short* __restrict__ D = WT + (size_t)mat * 262144;
#pragma unroll
    for (int i = 0; i < 16; ++i) {
      int id = i * 256 + t, r = id >> 6, c = id & 63;
      tile[r][c] = S[(size_t)(k0 + r) * Kd + (n0 + c)];
    }
    __syncthreads();
#pragma unroll
    for (int i = 0; i < 16; ++i) {
      int id = i * 256 + t, r = id >> 6, c = id & 63;
      D[(size_t)(n0 + r) * Kd + (k0 + c)] = f2bf(tile[c][r]);
    }
  } else if (blk < 3520) {
    const bool isB = blk < 3008;
    const float* enc = isB ? benc : cenc;
    unsigned short* out = isB ? XB0 : XC0;
    const int Lshift = isB ? 9 : 7;
    int i4 = (blk - (isB ? 960 : 3008)) * 256 + t;
    int row = i4 >> 7, c4 = (i4 & 127) << 2;
    float4 v;
    if (c4 < 256) v = *(const float4*)(enc + ((size_t)row << 8) + c4);
    else          v = *(const float4*)(cs + ((size_t)(row >> Lshift) << 8) + (c4 - 256));
    union { unsigned short u[4]; uint2 w; } o;
    o.u[0] = f2bf(v.x); o.u[1] = f2bf(v.y); o.u[2] = f2bf(v.z); o.u[3] = f2bf(v.w);
    *(uint2*)(out + ((size_t)row << 9) + c4) = o.w;
  } else {
    int b = blk - 3520, h = t;
    float acc = abq[h];
    for (int k = 0; k < 256; ++k) acc += cs[b * 256 + k] * aWq[k * 256 + h];
    wqa[b * 256 + h] = acc;
  }
}

// ---------------- merged MFMA GEMM launcher ------------------------------------
// epi: 0 plain f32 (+bias if B0), 1 highway bf16 (NB=3), 2 f32 exp(2*(x+b)),
//      3 f32 exp(2*x) transposed [b][col][row&127]
struct GJob {
  const unsigned short* A; const unsigned short* W0;
  const unsigned short* W1; const unsigned short* W2;
  const float* B0; const float* B1; const float* B2;
  void* Y; int lda, N, K, nbxs /*log2 blocks in x*/, epi, nb, blk0;
};

template <int NB>
__device__ __forceinline__ void gemm_body(const GJob& j, int bx, int by,
                                          unsigned short* sm, int t) {
  const int m0 = by * 64, n0 = bx * 64;
  const int lane = t & 63, wid = t >> 6;
  const int wr = wid >> 1, wc = wid & 1;
  const int N = j.N, K = j.K, lda = j.lda;

  const int srow = t >> 3;
  const int cg = (t & 7) ^ (srow & 7);
  const unsigned short* Ag0 = j.A + (size_t)(m0 + srow) * lda + cg * 8;
  const unsigned short* Ag1 = j.A + (size_t)(m0 + 32 + srow) * lda + cg * 8;
  const unsigned short* Wp[3] = {j.W0, j.W1, j.W2};
  const unsigned short* Bg0[NB], * Bg1[NB];
#pragma unroll
  for (int p = 0; p < NB; ++p) {
    Bg0[p] = Wp[p] + (size_t)(n0 + srow) * K + cg * 8;
    Bg1[p] = Wp[p] + (size_t)(n0 + 32 + srow) * K + cg * 8;
  }
  const int d0 = t * 8, d1 = (256 + t) * 8;

  const int fl = lane & 15, lg = lane >> 4;
  int offA[2][2], offB[2][2];
#pragma unroll
  for (int f = 0; f < 2; ++f) {
    int ra = wr * 32 + f * 16 + fl;
    int rb = wc * 32 + f * 16 + fl;
#pragma unroll
    for (int ks = 0; ks < 2; ++ks) {
      offA[f][ks] = ra * 64 + ((((ks << 2) + lg) ^ (ra & 7)) << 3);
      offB[f][ks] = rb * 64 + ((((ks << 2) + lg) ^ (rb & 7)) << 3);
    }
  }

  f32x4 acc[NB][2][2];
#pragma unroll
  for (int p = 0; p < NB; ++p)
#pragma unroll
    for (int i = 0; i < 2; ++i)
#pragma unroll
      for (int q = 0; q < 2; ++q) acc[p][i][q] = (f32x4){0.f, 0.f, 0.f, 0.f};

  ushort8 ra0 = *(const ushort8*)Ag0, ra1 = *(const ushort8*)Ag1;
  ushort8 rb0[NB], rb1[NB];
#pragma unroll
  for (int p = 0; p < NB; ++p) { rb0[p] = *(const ushort8*)Bg0[p]; rb1[p] = *(const ushort8*)Bg1[p]; }

  for (int k0 = 0; k0 < K; k0 += 64) {
    __syncthreads();
    *(ushort8*)&sm[d0] = ra0;
    *(ushort8*)&sm[d1] = ra1;
#pragma unroll
    for (int p = 0; p < NB; ++p) {
      unsigned short* Bs = sm + (1 + p) * 4096;
      *(ushort8*)&Bs[d0] = rb0[p];
      *(ushort8*)&Bs[d1] = rb1[p];
    }
    __syncthreads();
    if (k0 + 64 < K) {
      ra0 = *(const ushort8*)(Ag0 + k0 + 64);
      ra1 = *(const ushort8*)(Ag1 + k0 + 64);
#pragma unroll
      for (int p = 0; p < NB; ++p) {
        rb0[p] = *(const ushort8*)(Bg0[p] + k0 + 64);
        rb1[p] = *(const ushort8*)(Bg1[p] + k0 + 64);
      }
    }
#pragma unroll
    for (int ks = 0; ks < 2; ++ks) {
      ushort8 a0 = *(const ushort8*)&sm[offA[0][ks]];
      ushort8 a1 = *(const ushort8*)&sm[offA[1][ks]];
#pragma unroll
      for (int p = 0; p < NB; ++p) {
        const unsigned short* Bs = sm + (1 + p) * 4096;
        ushort8 b0 = *(const ushort8*)&Bs[offB[0][ks]];
        ushort8 b1 = *(const ushort8*)&Bs[offB[1][ks]];
        acc[p][0][0] = mfma_bf16(a0, b0, acc[p][0][0]);
        acc[p][0][1] = mfma_bf16(a0, b1, acc[p][0][1]);
        acc[p][1][0] = mfma_bf16(a1, b0, acc[p][1][0]);
        acc[p][1][1] = mfma_bf16(a1, b1, acc[p][1][1]);
      }
    }
  }
  asm volatile("s_nop 7\n\ts_nop 7" ::);   // MFMA -> VALU read hazard guard

#pragma unroll
  for (int mf = 0; mf < 2; ++mf) {
#pragma unroll
    for (int nf = 0; nf < 2; ++nf) {
      const int col = n0 + wc * 32 + nf * 16 + fl;
      const int row0 = m0 + wr * 32 + mf * 16 + lg * 4;
      if constexpr (NB == 3) {
        // epi == 1
        float bn = j.B0[col], bl = j.B1[col], bg = j.B2[col];
        unsigned short* Y = (unsigned short*)j.Y;
#pragma unroll
        for (int e = 0; e < 4; ++e) {
          float nv = acc[0][mf][nf][e] + bn;
          float lv = acc[1][mf][nf][e] + bl;
          float gv = fsigmoid(acc[2][mf][nf][e] + bg);
          Y[(size_t)(row0 + e) * N + col] = f2bf(gv * fmaxf(nv, 0.f) + (1.f - gv) * lv);
        }
      } else {
        float* Y = (float*)j.Y;
        if (j.epi == 2) {
          float bb = j.B0[col];
#pragma unroll
          for (int e = 0; e < 4; ++e)
            Y[(size_t)(row0 + e) * N + col] = __expf(2.0f * (acc[0][mf][nf][e] + bb));
        } else if (j.epi == 3) {
          f32x4 w;
#pragma unroll
          for (int e = 0; e < 4; ++e) w[e] = __expf(2.0f * acc[0][mf][nf][e]);
          *(f32x4*)(Y + (((size_t)(row0 >> 7)) << 16) + ((size_t)col << 7) + (row0 & 127)) = w;
        } else {
          float bb = j.B0 ? j.B0[col] : 0.f;
#pragma unroll
          for (int e = 0; e < 4; ++e)
            Y[(size_t)(row0 + e) * N + col] = acc[0][mf][nf][e] + bb;
        }
      }
    }
  }
}

// merged kernel: up to 3 gemm jobs + optional tscore tail blocks
__global__ __launch_bounds__(256) void mgemm3_k(GJob j0, GJob j1, GJob j2, int toff,
    const float* __restrict__ uha, const float* __restrict__ wqa,
    const float* __restrict__ av, float* __restrict__ tout) {
  __shared__ unsigned short sm[4 * 4096];
  const int blk = blockIdx.x, t = threadIdx.x;
  if (blk >= toff) {
    // tscore: t[pos] = sum_h tanh(wqa[b,h]+uha[pos,h])*av[h]
    const int lane = t & 63, wid = t >> 6;
    const int pos = (blk - toff) * 4 + wid;
    const int b = pos >> 9;
    const int h0 = lane << 2;
    float4 u = *(const float4*)(uha + (size_t)pos * 256 + h0);
    float4 w = *(const float4*)(wqa + b * 256 + h0);
    float4 v = *(const float4*)(av + h0);
    float s = ftanh(w.x + u.x) * v.x + ftanh(w.y + u.y) * v.y +
              ftanh(w.z + u.z) * v.z + ftanh(w.w + u.w) * v.w;
#pragma unroll
    for (int off = 32; off; off >>= 1) s += __shfl_xor(s, off);
    if (lane == 0) tout[pos] = s;
    return;
  }
  GJob j = j0;
  if (blk >= j1.blk0) j = j1;
  if (blk >= j2.blk0) j = j2;
  const int rel = blk - j.blk0;
  const int bx = rel & ((1 << j.nbxs) - 1), by = rel >> j.nbxs;
  if (j.nb == 3) gemm_body<3>(j, bx, by, sm, t);
  else          gemm_body<1>(j, bx, by, sm, t);
}

// -------- m-score v5: LDS-free, global u-reads (UHT is L2-resident) ------------
// tanh(a+b) = 1 - 2/(1 + e^{2a} e^{2b});  b_score[row] = V - 2*min_j sum_h v/(1+Ew*Eu)
// wave = (row-quad rq, h-quarter hq); lane owns j-pair (j = 2*lane, 2*lane+1).
// Per h: one wave-load of UHT[b][h][0..127] = 512B coalesced. e,v via scalar loads.
__global__ __launch_bounds__(512) void mscore_k(const float* __restrict__ EW,   // 4096x512
                                                const float* __restrict__ UHT,  // 8x512x128
                                                const float* __restrict__ mv,   // 512
                                                float* __restrict__ bscore) {   // 4096
  __shared__ float part[2][4][4][128];   // [rq][hq][row][j] = 16KB
  const int t = threadIdx.x, lane = t & 63, w = t >> 6;
  const int rq = w & 1, hq = w >> 1;     // 2 row-quads x 4 h-quarters
  const int blk = blockIdx.x;            // 512 blocks, 8 rows each
  const int row0 = __builtin_amdgcn_readfirstlane(blk * 8 + rq * 4);
  const int b = row0 >> 9;
  const float* __restrict__ ew = EW + ((size_t)row0 << 9) + hq * 128;  // 4 rows
  const float* __restrict__ vv = mv + hq * 128;
  const float* __restrict__ up = UHT + ((size_t)b << 16) + ((size_t)(hq * 128) << 7) + (lane << 1);

  float2 acc0 = {0.f, 0.f}, acc1 = {0.f, 0.f}, acc2 = {0.f, 0.f}, acc3 = {0.f, 0.f};

  // batches of 4 h; named A/B register double-buffer (static indexing only)
  float2 uA[4], uB[4];
  float eA[16], eB[16], vA[4], vB[4];

#define LOADB(BUF, h0_)                                              \
  {                                                                  \
    const int h0 = (h0_);                                            \
    _Pragma("unroll") for (int hh = 0; hh < 4; ++hh)                 \
        BUF##_u[hh] = *(const float2*)(up + ((size_t)(h0 + hh) << 7)); \
    _Pragma("unroll") for (int r = 0; r < 4; ++r)                    \
      _Pragma("unroll") for (int hh = 0; hh < 4; ++hh)               \
        BUF##_e[r * 4 + hh] = ew[(r << 9) + h0 + hh];                \
    _Pragma("unroll") for (int hh = 0; hh < 4; ++hh)                 \
        BUF##_v[hh] = vv[h0 + hh];                                   \
  }
#define A_u uA
#define A_e eA
#define A_v vA
#define B_u uB
#define B_e eB
#define B_v vB
#define COMP(BUF)                                                            \
  {                                                                          \
    _Pragma("unroll") for (int hh = 0; hh < 4; ++hh) {                       \
      float vvv = BUF##_v[hh];                                               \
      float2 u = BUF##_u[hh];                                                \
      float e0 = BUF##_e[0 * 4 + hh], e1 = BUF##_e[1 * 4 + hh];              \
      float e2 = BUF##_e[2 * 4 + hh], e3 = BUF##_e[3 * 4 + hh];              \
      acc0.x += vvv * __builtin_amdgcn_rcpf(__builtin_fmaf(e0, u.x, 1.f));   \
      acc0.y += vvv * __builtin_amdgcn_rcpf(__builtin_fmaf(e0, u.y, 1.f));   \
      acc1.x += vvv * __builtin_amdgcn_rcpf(__builtin_fmaf(e1, u.x, 1.f));   \
      acc1.y += vvv * __builtin_amdgcn_rcpf(__builtin_fmaf(e1, u.y, 1.f));   \
      acc2.x += vvv * __builtin_amdgcn_rcpf(__builtin_fmaf(e2, u.x, 1.f));   \
      acc2.y += vvv * __builtin_amdgcn_rcpf(__builtin_fmaf(e2, u.y, 1.f));   \
      acc3.x += vvv * __builtin_amdgcn_rcpf(__builtin_fmaf(e3, u.x, 1.f));   \
      acc3.y += vvv * __builtin_amdgcn_rcpf(__builtin_fmaf(e3, u.y, 1.f));   \
    }                                                                        \
  }

  LOADB(A, 0)
#pragma unroll
  for (int i = 0; i < 32; i += 2) {
    if (i + 1 < 32) LOADB(B, (i + 1) * 4)
    COMP(A)
    if (i + 2 < 32) LOADB(A, (i + 2) * 4)
    COMP(B)
  }
#undef LOADB
#undef COMP

  // write partials
  *(float2*)&part[rq][hq][0][lane << 1] = acc0;
  *(float2*)&part[rq][hq][1][lane << 1] = acc1;
  *(float2*)&part[rq][hq][2][lane << 1] = acc2;
  *(float2*)&part[rq][hq][3][lane << 1] = acc3;
  __syncthreads();

  if (w < 2) {
    // V = sum_h mv[h]
    float V = 0.f;
#pragma unroll
    for (int k = 0; k < 8; ++k) V += mv[lane + (k << 6)];
#pragma unroll
    for (int off = 32; off; off >>= 1) V += __shfl_xor(V, off);

    float mr[4];
#pragma unroll
    for (int r = 0; r < 4; ++r) {
      float2 s0 = *(const float2*)&part[w][0][r][lane << 1];
      float2 s1 = *(const float2*)&part[w][1][r][lane << 1];
      float2 s2 = *(const float2*)&part[w][2][r][lane << 1];
      float2 s3 = *(const float2*)&part[w][3][r][lane << 1];
      float sx = s0.x + s1.x + s2.x + s3.x;
      float sy = s0.y + s1.y + s2.y + s3.y;
      mr[r] = fminf(sx, sy);
    }
#pragma unroll
    for (int off = 32; off; off >>= 1) {
#pragma unroll
      for (int r = 0; r < 4; ++r) mr[r] = fminf(mr[r], __shfl_xor(mr[r], off));
    }
    if (lane == 0) {
      const int ro = blk * 8 + w * 4;
#pragma unroll
      for (int r = 0; r < 4; ++r) bscore[ro + r] = V - 2.f * mr[r];
    }
  }
}

// -------- per-segment softmax over window of t, weighted sum of b_enc rows -----
__global__ __launch_bounds__(256) void seg_k(const float* __restrict__ t,
                                             const float* __restrict__ bscore,
                                             const float* __restrict__ benc,
                                             float* __restrict__ seg,
                                             float* __restrict__ sco) {
  const int s = blockIdx.x, b = blockIdx.y, h = threadIdx.x;
  int i, n;
  if (s < 102)      { i = 0; n = s; }
  else if (s < 203) { i = 1; n = s - 102; }
  else if (s < 303) { i = 2; n = s - 203; }
  else              { i = 3; n = s - 303; }
  const int ws = 5 * (i + 1), start = n * 5;
  const float* tb = t + b * 512 + start;
  float mx = -3.0e38f;
  for (int w = 0; w < ws; ++w) mx = fmaxf(mx, tb[w]);
  float sum = 0.f;
  for (int w = 0; w < ws; ++w) sum += __expf(tb[w] - mx);
  float inv = 1.f / sum;
  float acc = 0.f;
  for (int w = 0; w < ws; ++w)
    acc += __expf(tb[w] - mx) * benc[((size_t)(b * 512 + start + w)) * 256 + h];
  seg[((size_t)(b * 402 + s)) * 256 + h] = acc * inv;
  if (h == 0) {
    float ss = 0.f;
    const float* bs = bscore + b * 512 + start;
    for (int w = 0; w < ws; ++w) ss += bs[w];
    sco[b * 402 + s] = ss;
  }
}

// -------- final: s_score = softmax(scores); out = s_score @ segments -----------
__global__ __launch_bounds__(256) void final_k(const float* __restrict__ sco,
                                               const float* __restrict__ seg,
                                               float* __restrict__ dout) {
  const int b = blockIdx.x, tid = threadIdx.x, lane = tid & 63, wid = tid >> 6;
  __shared__ float sc[402];
  __shared__ float redm[4], reds[4];
  for (int s = tid; s < 402; s += 256) sc[s] = sco[b * 402 + s];
  __syncthreads();
  float m = -3.0e38f;
  for (int s = tid; s < 402; s += 256) m = fmaxf(m, sc[s]);
#pragma unroll
  for (int off = 32; off; off >>= 1) m = fmaxf(m, __shfl_xor(m, off));
  if (lane == 0) redm[wid] = m;
  __syncthreads();
  m = fmaxf(fmaxf(redm[0], redm[1]), fmaxf(redm[2], redm[3]));
  float p = 0.f;
  for (int s = tid; s < 402; s += 256) p += __expf(sc[s] - m);
#pragma unroll
  for (int off = 32; off; off >>= 1) p += __shfl_xor(p, off);
  if (lane == 0) reds[wid] = p;
  __syncthreads();
  float invS = 1.f / (reds[0] + reds[1] + reds[2] + reds[3]);
  for (int s = tid; s < 402; s += 256) {
    float pv = __expf(sc[s] - m) * invS;
    dout[2048 + b * 402 + s] = pv;
    sc[s] = pv;
  }
  __syncthreads();
  float acc = 0.f;
  for (int s = 0; s < 402; ++s)
    acc += sc[s] * seg[((size_t)(b * 402 + s)) * 256 + tid];
  dout[b * 256 + tid] = acc;
}

extern "C" void kernel_launch(void* const* d_in, const int* in_sizes, int n_in,
                              void* d_out, int out_size, void* d_ws, size_t ws_size,
                              hipStream_t stream) {
  const float* b_enc   = (const float*)d_in[0];
  const float* c_enc   = (const float*)d_in[1];
  const float* c_state = (const float*)d_in[2];
  const float* bh_Wn = (const float*)d_in[5];
  const float* bh_bn = (const float*)d_in[6];
  const float* bh_Wl = (const float*)d_in[7];
  const float* bh_bl = (const float*)d_in[8];
  const float* bh_Wg = (const float*)d_in[9];
  const float* bh_bg = (const float*)d_in[10];
  const float* ch_Wn = (const float*)d_in[11];
  const float* ch_bn = (const float*)d_in[12];
  const float* ch_Wl = (const float*)d_in[13];
  const float* ch_bl = (const float*)d_in[14];
  const float* ch_Wg = (const float*)d_in[15];
  const float* ch_bg = (const float*)d_in[16];
  const float* m_Wq  = (const float*)d_in[17];
  const float* m_bq  = (const float*)d_in[18];
  const float* m_Wk  = (const float*)d_in[19];
  const float* m_v   = (const float*)d_in[20];
  const float* a_Wq  = (const float*)d_in[21];
  const float* a_bq  = (const float*)d_in[22];
  const float* a_Wk  = (const float*)d_in[23];
  const float* a_v   = (const float*)d_in[24];

  uint8_t* base = (uint8_t*)d_ws;
  unsigned short* WT  = (unsigned short*)(base);            // 14 x 512x512 bf16
  unsigned short* WTa = WT + 14 * 262144;                   // 256x256 bf16
  unsigned short* XB0 = (unsigned short*)(base + 7471104);  // 4096x512 bf16
  unsigned short* XB1 = (unsigned short*)(base + 11665408); // 4096x512 bf16
  unsigned short* XC0 = (unsigned short*)(base + 15859712); // 1024x512 bf16
  unsigned short* XC1 = (unsigned short*)(base + 16908288); // 1024x512 bf16
  float* EW   = (float*)(base + 17956864);                  // 4096x512 f32
  float* UHT  = (float*)(base + 26345472);                  // 8x512x128 f32
  float* UHA  = (float*)(base + 28442624);                  // 4096x256 f32
  float* WQA  = (float*)(base + 32636928);
  float* T    = (float*)(base + 32645120);
  float* SEG  = (float*)(base + 32661504);                  // 8x402x256 f32
  float* SCO  = (float*)(base + 35954688);

  float* out = (float*)d_out;
  float* BSC = out + 5264;

  const int S = 262144;
  const int LW = 262144;
  const int SENT = 1 << 30;

  WArg wa;
  wa.s[0] = bh_Wn; wa.s[1] = bh_Wn + LW;
  wa.s[2] = bh_Wl; wa.s[3] = bh_Wl + LW;
  wa.s[4] = bh_Wg; wa.s[5] = bh_Wg + LW;
  wa.s[6] = ch_Wn; wa.s[7] = ch_Wn + LW;
  wa.s[8] = ch_Wl; wa.s[9] = ch_Wl + LW;
  wa.s[10] = ch_Wg; wa.s[11] = ch_Wg + LW;
  wa.s[12] = m_Wq; wa.s[13] = m_Wk; wa.s[14] = a_Wk;

  prep_k<<<3528, 256, 0, stream>>>(wa, WT, b_enc, c_enc, c_state, XB0, XC0,
                                   a_Wq, a_bq, WQA);

  // G1: highway-b L1 (512 blk) + highway-c L1 (128 blk) + UHA gemm (256 blk)
  {
    GJob jb = {XB0, WT, WT + 2 * S, WT + 4 * S, bh_bn, bh_bl, bh_bg,
               XB1, 512, 512, 512, 3, 1, 3, 0};
    GJob jc = {XC0, WT + 6 * S, WT + 8 * S, WT + 10 * S, ch_bn, ch_bl, ch_bg,
               XC1, 512, 512, 512, 3, 1, 3, 512};
    GJob ja = {XB0, WTa, nullptr, nullptr, nullptr, nullptr, nullptr,
               UHA, 512, 256, 256, 2, 0, 1, 640};
    mgemm3_k<<<896, 256, 0, stream>>>(jb, jc, ja, 896, nullptr, nullptr, nullptr, nullptr);
  }
  // G2: highway-b L2 (512) + highway-c L2 (128)
  {
    GJob jb = {XB1, WT + S, WT + 3 * S, WT + 5 * S, bh_bn + 512, bh_bl + 512, bh_bg + 512,
               XB0, 512, 512, 512, 3, 1, 3, 0};
    GJob jc = {XC1, WT + 7 * S, WT + 9 * S, WT + 11 * S, ch_bn + 512, ch_bl + 512, ch_bg + 512,
               XC0, 512, 512, 512, 3, 1, 3, 512};
    GJob js = jc; js.blk0 = SENT;
    mgemm3_k<<<640, 256, 0, stream>>>(jb, jc, js, 640, nullptr, nullptr, nullptr, nullptr);
  }
  // G3: EW gemm (512) + UHT gemm (128) + tscore tail (1024)
  {
    GJob je = {XB0, WT + 12 * S, nullptr, nullptr, m_bq, nullptr, nullptr,
               EW, 512, 512, 512, 3, 2, 1, 0};
    GJob ju = {XC0, WT + 13 * S, nullptr, nullptr, nullptr, nullptr, nullptr,
               UHT, 512, 512, 512, 3, 3, 1, 512};
    GJob js = ju; js.blk0 = SENT;
    mgemm3_k<<<1664, 256, 0, stream>>>(je, ju, js, 640, UHA, WQA, a_v, T);
  }

  mscore_k<<<512, 512, 0, stream>>>(EW, UHT, m_v, BSC);
  seg_k<<<dim3(402, 8), 256, 0, stream>>>(T, BSC, b_enc, SEG, SCO);
  final_k<<<8, 256, 0, stream>>>(SCO, SEG, out);
}

// Round 7
// 137.800 us; speedup vs baseline: 1.0514x; 1.0514x over previous
//
#include <hip/hip_runtime.h>
#include <hip/hip_bf16.h>
#include <cstdint>
#include <cstddef>

// Shapes (fixed): B=8, LB=512, LC=128, H=256, H2=512, MIN_WS=5, N_WIN=4
// Windows: ws=5,10,15,20 ; n_seg=102,101,100,99 ; total 402
// d_out: out[8*256] | s_score[8*402] | b_score[8*512]  (floats)

typedef unsigned short ushort8 __attribute__((ext_vector_type(8)));
typedef float f32x4 __attribute__((ext_vector_type(4)));
typedef float f32x2 __attribute__((ext_vector_type(2)));

__device__ __forceinline__ float fsigmoid(float x) { return 1.0f / (1.0f + __expf(-x)); }
__device__ __forceinline__ float ftanh(float x) {
  float e = __expf(2.0f * x);
  return 1.0f - 2.0f / (e + 1.0f);
}
__device__ __forceinline__ unsigned short f2bf(float x) {
  union { float f; unsigned u; } v; v.f = x;
  unsigned r = (v.u + 0x7FFFu + ((v.u >> 16) & 1u)) >> 16;
  return (unsigned short)r;
}
__device__ __forceinline__ f32x4 mfma_bf16(ushort8 a, ushort8 b, f32x4 c) {
  asm("v_mfma_f32_16x16x32_bf16 %0, %1, %2, %0" : "+v"(c) : "v"(a), "v"(b));
  return c;
}

// ---------------- prep: weight transpose/convert + concats + wqa ---------------
struct WArg { const float* s[15]; };
__global__ __launch_bounds__(256) void prep_k(WArg wa, unsigned short* __restrict__ WT,
    const float* __restrict__ benc, const float* __restrict__ cenc,
    const float* __restrict__ cs,
    unsigned short* __restrict__ XB0, unsigned short* __restrict__ XC0,
    const float* __restrict__ aWq, const float* __restrict__ abq,
    float* __restrict__ wqa) {
  __shared__ float tile[64][65];
  const int blk = blockIdx.x, t = threadIdx.x;
  if (blk < 960) {
    const int mat = blk >> 6, q = blk & 63;
    const int Kd = (mat == 14) ? 256 : 512;
    const int k0 = (q >> 3) << 6, n0 = (q & 7) << 6;
    if (mat == 14 && (k0 >= 256 || n0 >= 256)) return;
    const float* __restrict__ S = wa.s[mat];
    unsigned short* __restrict__ D = WT + (size_t)mat * 262144;
#pragma unroll
    for (int i = 0; i < 16; ++i) {
      int id = i * 256 + t, r = id >> 6, c = id & 63;
      tile[r][c] = S[(size_t)(k0 + r) * Kd + (n0 + c)];
    }
    __syncthreads();
#pragma unroll
    for (int i = 0; i < 16; ++i) {
      int id = i * 256 + t, r = id >> 6, c = id & 63;
      D[(size_t)(n0 + r) * Kd + (k0 + c)] = f2bf(tile[c][r]);
    }
  } else if (blk < 3520) {
    const bool isB = blk < 3008;
    const float* enc = isB ? benc : cenc;
    unsigned short* out = isB ? XB0 : XC0;
    const int Lshift = isB ? 9 : 7;
    int i4 = (blk - (isB ? 960 : 3008)) * 256 + t;
    int row = i4 >> 7, c4 = (i4 & 127) << 2;
    float4 v;
    if (c4 < 256) v = *(const float4*)(enc + ((size_t)row << 8) + c4);
    else          v = *(const float4*)(cs + ((size_t)(row >> Lshift) << 8) + (c4 - 256));
    union { unsigned short u[4]; uint2 w; } o;
    o.u[0] = f2bf(v.x); o.u[1] = f2bf(v.y); o.u[2] = f2bf(v.z); o.u[3] = f2bf(v.w);
    *(uint2*)(out + ((size_t)row << 9) + c4) = o.w;
  } else {
    int b = blk - 3520, h = t;
    float acc = abq[h];
    for (int k = 0; k < 256; ++k) acc += cs[b * 256 + k] * aWq[k * 256 + h];
    wqa[b * 256 + h] = acc;
  }
}

// ---------------- merged MFMA GEMM launcher ------------------------------------
// epi: 0 plain f32 (+bias if B0), 1 highway bf16 (NB=3), 2 f32 exp(2*(x+b)),
//      3 f32 exp(2*x) transposed [b][col][row&127]
struct GJob {
  const unsigned short* A; const unsigned short* W0;
  const unsigned short* W1; const unsigned short* W2;
  const float* B0; const float* B1; const float* B2;
  void* Y; int lda, N, K, nbxs /*log2 blocks in x*/, epi, nb, blk0;
};

template <int NB>
__device__ __forceinline__ void gemm_body(const GJob& j, int bx, int by,
                                          unsigned short* sm, int t) {
  const int m0 = by * 64, n0 = bx * 64;
  const int lane = t & 63, wid = t >> 6;
  const int wr = wid >> 1, wc = wid & 1;
  const int N = j.N, K = j.K, lda = j.lda;

  const int srow = t >> 3;
  const int cg = (t & 7) ^ (srow & 7);
  const unsigned short* Ag0 = j.A + (size_t)(m0 + srow) * lda + cg * 8;
  const unsigned short* Ag1 = j.A + (size_t)(m0 + 32 + srow) * lda + cg * 8;
  const unsigned short* Wp[3] = {j.W0, j.W1, j.W2};
  const unsigned short* Bg0[NB], * Bg1[NB];
#pragma unroll
  for (int p = 0; p < NB; ++p) {
    Bg0[p] = Wp[p] + (size_t)(n0 + srow) * K + cg * 8;
    Bg1[p] = Wp[p] + (size_t)(n0 + 32 + srow) * K + cg * 8;
  }
  const int d0 = t * 8, d1 = (256 + t) * 8;

  const int fl = lane & 15, lg = lane >> 4;
  int offA[2][2], offB[2][2];
#pragma unroll
  for (int f = 0; f < 2; ++f) {
    int ra = wr * 32 + f * 16 + fl;
    int rb = wc * 32 + f * 16 + fl;
#pragma unroll
    for (int ks = 0; ks < 2; ++ks) {
      offA[f][ks] = ra * 64 + ((((ks << 2) + lg) ^ (ra & 7)) << 3);
      offB[f][ks] = rb * 64 + ((((ks << 2) + lg) ^ (rb & 7)) << 3);
    }
  }

  f32x4 acc[NB][2][2];
#pragma unroll
  for (int p = 0; p < NB; ++p)
#pragma unroll
    for (int i = 0; i < 2; ++i)
#pragma unroll
      for (int q = 0; q < 2; ++q) acc[p][i][q] = (f32x4){0.f, 0.f, 0.f, 0.f};

  ushort8 ra0 = *(const ushort8*)Ag0, ra1 = *(const ushort8*)Ag1;
  ushort8 rb0[NB], rb1[NB];
#pragma unroll
  for (int p = 0; p < NB; ++p) { rb0[p] = *(const ushort8*)Bg0[p]; rb1[p] = *(const ushort8*)Bg1[p]; }

  for (int k0 = 0; k0 < K; k0 += 64) {
    __syncthreads();
    *(ushort8*)&sm[d0] = ra0;
    *(ushort8*)&sm[d1] = ra1;
#pragma unroll
    for (int p = 0; p < NB; ++p) {
      unsigned short* Bs = sm + (1 + p) * 4096;
      *(ushort8*)&Bs[d0] = rb0[p];
      *(ushort8*)&Bs[d1] = rb1[p];
    }
    __syncthreads();
    if (k0 + 64 < K) {
      ra0 = *(const ushort8*)(Ag0 + k0 + 64);
      ra1 = *(const ushort8*)(Ag1 + k0 + 64);
#pragma unroll
      for (int p = 0; p < NB; ++p) {
        rb0[p] = *(const ushort8*)(Bg0[p] + k0 + 64);
        rb1[p] = *(const ushort8*)(Bg1[p] + k0 + 64);
      }
    }
#pragma unroll
    for (int ks = 0; ks < 2; ++ks) {
      ushort8 a0 = *(const ushort8*)&sm[offA[0][ks]];
      ushort8 a1 = *(const ushort8*)&sm[offA[1][ks]];
#pragma unroll
      for (int p = 0; p < NB; ++p) {
        const unsigned short* Bs = sm + (1 + p) * 4096;
        ushort8 b0 = *(const ushort8*)&Bs[offB[0][ks]];
        ushort8 b1 = *(const ushort8*)&Bs[offB[1][ks]];
        acc[p][0][0] = mfma_bf16(a0, b0, acc[p][0][0]);
        acc[p][0][1] = mfma_bf16(a0, b1, acc[p][0][1]);
        acc[p][1][0] = mfma_bf16(a1, b0, acc[p][1][0]);
        acc[p][1][1] = mfma_bf16(a1, b1, acc[p][1][1]);
      }
    }
  }
  asm volatile("s_nop 7\n\ts_nop 7" ::);   // MFMA -> VALU read hazard guard

#pragma unroll
  for (int mf = 0; mf < 2; ++mf) {
#pragma unroll
    for (int nf = 0; nf < 2; ++nf) {
      const int col = n0 + wc * 32 + nf * 16 + fl;
      const int row0 = m0 + wr * 32 + mf * 16 + lg * 4;
      if constexpr (NB == 3) {
        // epi == 1
        float bn = j.B0[col], bl = j.B1[col], bg = j.B2[col];
        unsigned short* Y = (unsigned short*)j.Y;
#pragma unroll
        for (int e = 0; e < 4; ++e) {
          float nv = acc[0][mf][nf][e] + bn;
          float lv = acc[1][mf][nf][e] + bl;
          float gv = fsigmoid(acc[2][mf][nf][e] + bg);
          Y[(size_t)(row0 + e) * N + col] = f2bf(gv * fmaxf(nv, 0.f) + (1.f - gv) * lv);
        }
      } else {
        float* Y = (float*)j.Y;
        if (j.epi == 2) {
          float bb = j.B0[col];
#pragma unroll
          for (int e = 0; e < 4; ++e)
            Y[(size_t)(row0 + e) * N + col] = __expf(2.0f * (acc[0][mf][nf][e] + bb));
        } else if (j.epi == 3) {
          f32x4 w;
#pragma unroll
          for (int e = 0; e < 4; ++e) w[e] = __expf(2.0f * acc[0][mf][nf][e]);
          *(f32x4*)(Y + (((size_t)(row0 >> 7)) << 16) + ((size_t)col << 7) + (row0 & 127)) = w;
        } else {
          float bb = j.B0 ? j.B0[col] : 0.f;
#pragma unroll
          for (int e = 0; e < 4; ++e)
            Y[(size_t)(row0 + e) * N + col] = acc[0][mf][nf][e] + bb;
        }
      }
    }
  }
}

// merged kernel: up to 3 gemm jobs + optional tscore tail blocks
__global__ __launch_bounds__(256) void mgemm3_k(GJob j0, GJob j1, GJob j2, int toff,
    const float* __restrict__ uha, const float* __restrict__ wqa,
    const float* __restrict__ av, float* __restrict__ tout) {
  __shared__ unsigned short sm[4 * 4096];
  const int blk = blockIdx.x, t = threadIdx.x;
  if (blk >= toff) {
    // tscore: t[pos] = sum_h tanh(wqa[b,h]+uha[pos,h])*av[h]
    const int lane = t & 63, wid = t >> 6;
    const int pos = (blk - toff) * 4 + wid;
    const int b = pos >> 9;
    const int h0 = lane << 2;
    float4 u = *(const float4*)(uha + (size_t)pos * 256 + h0);
    float4 w = *(const float4*)(wqa + b * 256 + h0);
    float4 v = *(const float4*)(av + h0);
    float s = ftanh(w.x + u.x) * v.x + ftanh(w.y + u.y) * v.y +
              ftanh(w.z + u.z) * v.z + ftanh(w.w + u.w) * v.w;
#pragma unroll
    for (int off = 32; off; off >>= 1) s += __shfl_xor(s, off);
    if (lane == 0) tout[pos] = s;
    return;
  }
  GJob j = j0;
  if (blk >= j1.blk0) j = j1;
  if (blk >= j2.blk0) j = j2;
  const int rel = blk - j.blk0;
  const int bx = rel & ((1 << j.nbxs) - 1), by = rel >> j.nbxs;
  if (j.nb == 3) gemm_body<3>(j, bx, by, sm, t);
  else          gemm_body<1>(j, bx, by, sm, t);
}

// -------- m-score v6: global u-reads (L2-resident) + LDS-broadcast e/v ---------
// tanh(a+b) = 1 - 2/(1 + e^{2a} e^{2b});  b_score[row] = V - 2*min_j sum_h v/(1+Ew*Eu)
// wave = (row-quad rq, h-quarter hq); lane owns j-pair. u prefetched from global
// (vmcnt, in-order); e/v staged once in LDS, read per-batch via broadcast b128
// (in-order lgkm -> no full drains; the v5 s_load out-of-order drain bug is gone).
__global__ __launch_bounds__(512) void mscore_k(const float* __restrict__ EW,   // 4096x512
                                                const float* __restrict__ UHT,  // 8x512x128
                                                const float* __restrict__ mv,   // 512
                                                float* __restrict__ bscore) {   // 4096
  __shared__ float smem[8 * 512 + 512];   // ews[8][512] | vvs[512] ; part aliases ews
  const int t = threadIdx.x, lane = t & 63, w = t >> 6;
  const int rq = w & 1, hq = w >> 1;      // 2 row-quads x 4 h-quarters
  const int blk = blockIdx.x;             // 512 blocks, 8 rows each
  const int row0 = __builtin_amdgcn_readfirstlane(blk * 8);
  const int b = row0 >> 9;
  const float* __restrict__ up = UHT + ((size_t)b << 16) + ((size_t)(hq * 128) << 7) + (lane << 1);

  // stage 8 EW rows (1024 float4, 2/thread) + mv (128 float4)
#pragma unroll
  for (int q = 0; q < 2; ++q) {
    int f4 = q * 512 + t, r = f4 >> 7, c4 = (f4 & 127) << 2;
    *(float4*)&smem[r * 512 + c4] = *(const float4*)(EW + (((size_t)(row0 + r)) << 9) + c4);
  }
  if (t < 128) *(float4*)&smem[4096 + (t << 2)] = *(const float4*)(mv + (t << 2));
  __syncthreads();

  const float* __restrict__ eb = &smem[(rq * 4) * 512 + hq * 128];  // 4 rows, row stride 512
  const float* __restrict__ vb = &smem[4096 + hq * 128];

  f32x2 acc0 = {0.f, 0.f}, acc1 = {0.f, 0.f}, acc2 = {0.f, 0.f}, acc3 = {0.f, 0.f};
  f32x2 uA[4], uB[4];

#define LOADU(U, h0_)                                                      \
  { _Pragma("unroll") for (int hh = 0; hh < 4; ++hh)                       \
      U[hh] = *(const f32x2*)(up + ((size_t)((h0_) + hh) << 7)); }
#define COMPB(U, h0_)                                                      \
  {                                                                        \
    f32x4 e0 = *(const f32x4*)(eb + 0 * 512 + (h0_));                      \
    f32x4 e1 = *(const f32x4*)(eb + 1 * 512 + (h0_));                      \
    f32x4 e2 = *(const f32x4*)(eb + 2 * 512 + (h0_));                      \
    f32x4 e3 = *(const f32x4*)(eb + 3 * 512 + (h0_));                      \
    f32x4 v4 = *(const f32x4*)(vb + (h0_));                                \
    _Pragma("unroll") for (int hh = 0; hh < 4; ++hh) {                     \
      float vvv = v4[hh];                                                  \
      f32x2 u = U[hh];                                                     \
      acc0.x += vvv * __builtin_amdgcn_rcpf(__builtin_fmaf(e0[hh], u.x, 1.f)); \
      acc0.y += vvv * __builtin_amdgcn_rcpf(__builtin_fmaf(e0[hh], u.y, 1.f)); \
      acc1.x += vvv * __builtin_amdgcn_rcpf(__builtin_fmaf(e1[hh], u.x, 1.f)); \
      acc1.y += vvv * __builtin_amdgcn_rcpf(__builtin_fmaf(e1[hh], u.y, 1.f)); \
      acc2.x += vvv * __builtin_amdgcn_rcpf(__builtin_fmaf(e2[hh], u.x, 1.f)); \
      acc2.y += vvv * __builtin_amdgcn_rcpf(__builtin_fmaf(e2[hh], u.y, 1.f)); \
      acc3.x += vvv * __builtin_amdgcn_rcpf(__builtin_fmaf(e3[hh], u.x, 1.f)); \
      acc3.y += vvv * __builtin_amdgcn_rcpf(__builtin_fmaf(e3[hh], u.y, 1.f)); \
    }                                                                      \
  }

  LOADU(uA, 0)
#pragma unroll
  for (int i = 0; i < 32; i += 2) {
    LOADU(uB, (i + 1) * 4)
    COMPB(uA, i * 4)
    if (i + 2 < 32) LOADU(uA, (i + 2) * 4)
    COMPB(uB, (i + 1) * 4)
  }
#undef LOADU
#undef COMPB

  // part[rq][hq][r][j] aliases ews region (16KB); e-reads are done.
  __syncthreads();
  float* part = smem;
  {
    const int base = ((rq * 4 + hq) * 4) * 128 + (lane << 1);
    *(f32x2*)&part[base + 0 * 128] = acc0;
    *(f32x2*)&part[base + 1 * 128] = acc1;
    *(f32x2*)&part[base + 2 * 128] = acc2;
    *(f32x2*)&part[base + 3 * 128] = acc3;
  }
  __syncthreads();

  if (w < 2) {
    // V = sum_h mv[h] (vvs region still intact at smem+4096)
    float V = 0.f;
#pragma unroll
    for (int k = 0; k < 8; ++k) V += smem[4096 + lane + (k << 6)];
#pragma unroll
    for (int off = 32; off; off >>= 1) V += __shfl_xor(V, off);

    float mr[4];
#pragma unroll
    for (int r = 0; r < 4; ++r) {
      f32x2 s0 = *(const f32x2*)&part[((w * 4 + 0) * 4 + r) * 128 + (lane << 1)];
      f32x2 s1 = *(const f32x2*)&part[((w * 4 + 1) * 4 + r) * 128 + (lane << 1)];
      f32x2 s2 = *(const f32x2*)&part[((w * 4 + 2) * 4 + r) * 128 + (lane << 1)];
      f32x2 s3 = *(const f32x2*)&part[((w * 4 + 3) * 4 + r) * 128 + (lane << 1)];
      float sx = s0.x + s1.x + s2.x + s3.x;
      float sy = s0.y + s1.y + s2.y + s3.y;
      mr[r] = fminf(sx, sy);
    }
#pragma unroll
    for (int off = 32; off; off >>= 1) {
#pragma unroll
      for (int r = 0; r < 4; ++r) mr[r] = fminf(mr[r], __shfl_xor(mr[r], off));
    }
    if (lane == 0) {
      const int ro = blk * 8 + w * 4;
#pragma unroll
      for (int r = 0; r < 4; ++r) bscore[ro + r] = V - 2.f * mr[r];
    }
  }
}

// -------- per-segment softmax over window of t, weighted sum of b_enc rows -----
__global__ __launch_bounds__(256) void seg_k(const float* __restrict__ t,
                                             const float* __restrict__ bscore,
                                             const float* __restrict__ benc,
                                             float* __restrict__ seg,
                                             float* __restrict__ sco) {
  const int s = blockIdx.x, b = blockIdx.y, h = threadIdx.x;
  int i, n;
  if (s < 102)      { i = 0; n = s; }
  else if (s < 203) { i = 1; n = s - 102; }
  else if (s < 303) { i = 2; n = s - 203; }
  else              { i = 3; n = s - 303; }
  const int ws = 5 * (i + 1), start = n * 5;
  const float* tb = t + b * 512 + start;
  float mx = -3.0e38f;
  for (int w = 0; w < ws; ++w) mx = fmaxf(mx, tb[w]);
  float sum = 0.f;
  for (int w = 0; w < ws; ++w) sum += __expf(tb[w] - mx);
  float inv = 1.f / sum;
  float acc = 0.f;
  for (int w = 0; w < ws; ++w)
    acc += __expf(tb[w] - mx) * benc[((size_t)(b * 512 + start + w)) * 256 + h];
  seg[((size_t)(b * 402 + s)) * 256 + h] = acc * inv;
  if (h == 0) {
    float ss = 0.f;
    const float* bs = bscore + b * 512 + start;
    for (int w = 0; w < ws; ++w) ss += bs[w];
    sco[b * 402 + s] = ss;
  }
}

// -------- final: s_score = softmax(scores); out = s_score @ segments -----------
__global__ __launch_bounds__(256) void final_k(const float* __restrict__ sco,
                                               const float* __restrict__ seg,
                                               float* __restrict__ dout) {
  const int b = blockIdx.x, tid = threadIdx.x, lane = tid & 63, wid = tid >> 6;
  __shared__ float sc[402];
  __shared__ float redm[4], reds[4];
  for (int s = tid; s < 402; s += 256) sc[s] = sco[b * 402 + s];
  __syncthreads();
  float m = -3.0e38f;
  for (int s = tid; s < 402; s += 256) m = fmaxf(m, sc[s]);
#pragma unroll
  for (int off = 32; off; off >>= 1) m = fmaxf(m, __shfl_xor(m, off));
  if (lane == 0) redm[wid] = m;
  __syncthreads();
  m = fmaxf(fmaxf(redm[0], redm[1]), fmaxf(redm[2], redm[3]));
  float p = 0.f;
  for (int s = tid; s < 402; s += 256) p += __expf(sc[s] - m);
#pragma unroll
  for (int off = 32; off; off >>= 1) p += __shfl_xor(p, off);
  if (lane == 0) reds[wid] = p;
  __syncthreads();
  float invS = 1.f / (reds[0] + reds[1] + reds[2] + reds[3]);
  for (int s = tid; s < 402; s += 256) {
    float pv = __expf(sc[s] - m) * invS;
    dout[2048 + b * 402 + s] = pv;
    sc[s] = pv;
  }
  __syncthreads();
  float acc = 0.f;
  for (int s = 0; s < 402; ++s)
    acc += sc[s] * seg[((size_t)(b * 402 + s)) * 256 + tid];
  dout[b * 256 + tid] = acc;
}

extern "C" void kernel_launch(void* const* d_in, const int* in_sizes, int n_in,
                              void* d_out, int out_size, void* d_ws, size_t ws_size,
                              hipStream_t stream) {
  const float* b_enc   = (const float*)d_in[0];
  const float* c_enc   = (const float*)d_in[1];
  const float* c_state = (const float*)d_in[2];
  const float* bh_Wn = (const float*)d_in[5];
  const float* bh_bn = (const float*)d_in[6];
  const float* bh_Wl = (const float*)d_in[7];
  const float* bh_bl = (const float*)d_in[8];
  const float* bh_Wg = (const float*)d_in[9];
  const float* bh_bg = (const float*)d_in[10];
  const float* ch_Wn = (const float*)d_in[11];
  const float* ch_bn = (const float*)d_in[12];
  const float* ch_Wl = (const float*)d_in[13];
  const float* ch_bl = (const float*)d_in[14];
  const float* ch_Wg = (const float*)d_in[15];
  const float* ch_bg = (const float*)d_in[16];
  const float* m_Wq  = (const float*)d_in[17];
  const float* m_bq  = (const float*)d_in[18];
  const float* m_Wk  = (const float*)d_in[19];
  const float* m_v   = (const float*)d_in[20];
  const float* a_Wq  = (const float*)d_in[21];
  const float* a_bq  = (const float*)d_in[22];
  const float* a_Wk  = (const float*)d_in[23];
  const float* a_v   = (const float*)d_in[24];

  uint8_t* base = (uint8_t*)d_ws;
  unsigned short* WT  = (unsigned short*)(base);            // 14 x 512x512 bf16
  unsigned short* WTa = WT + 14 * 262144;                   // 256x256 bf16
  unsigned short* XB0 = (unsigned short*)(base + 7471104);  // 4096x512 bf16
  unsigned short* XB1 = (unsigned short*)(base + 11665408); // 4096x512 bf16
  unsigned short* XC0 = (unsigned short*)(base + 15859712); // 1024x512 bf16
  unsigned short* XC1 = (unsigned short*)(base + 16908288); // 1024x512 bf16
  float* EW   = (float*)(base + 17956864);                  // 4096x512 f32
  float* UHT  = (float*)(base + 26345472);                  // 8x512x128 f32
  float* UHA  = (float*)(base + 28442624);                  // 4096x256 f32
  float* WQA  = (float*)(base + 32636928);
  float* T    = (float*)(base + 32645120);
  float* SEG  = (float*)(base + 32661504);                  // 8x402x256 f32
  float* SCO  = (float*)(base + 35954688);

  float* out = (float*)d_out;
  float* BSC = out + 5264;

  const int S = 262144;
  const int LW = 262144;
  const int SENT = 1 << 30;

  WArg wa;
  wa.s[0] = bh_Wn; wa.s[1] = bh_Wn + LW;
  wa.s[2] = bh_Wl; wa.s[3] = bh_Wl + LW;
  wa.s[4] = bh_Wg; wa.s[5] = bh_Wg + LW;
  wa.s[6] = ch_Wn; wa.s[7] = ch_Wn + LW;
  wa.s[8] = ch_Wl; wa.s[9] = ch_Wl + LW;
  wa.s[10] = ch_Wg; wa.s[11] = ch_Wg + LW;
  wa.s[12] = m_Wq; wa.s[13] = m_Wk; wa.s[14] = a_Wk;

  prep_k<<<3528, 256, 0, stream>>>(wa, WT, b_enc, c_enc, c_state, XB0, XC0,
                                   a_Wq, a_bq, WQA);

  // G1: highway-b L1 (512 blk) + highway-c L1 (128 blk) + UHA gemm (256 blk)
  {
    GJob jb = {XB0, WT, WT + 2 * S, WT + 4 * S, bh_bn, bh_bl, bh_bg,
               XB1, 512, 512, 512, 3, 1, 3, 0};
    GJob jc = {XC0, WT + 6 * S, WT + 8 * S, WT + 10 * S, ch_bn, ch_bl, ch_bg,
               XC1, 512, 512, 512, 3, 1, 3, 512};
    GJob ja = {XB0, WTa, nullptr, nullptr, nullptr, nullptr, nullptr,
               UHA, 512, 256, 256, 2, 0, 1, 640};
    mgemm3_k<<<896, 256, 0, stream>>>(jb, jc, ja, 896, nullptr, nullptr, nullptr, nullptr);
  }
  // G2: highway-b L2 (512) + highway-c L2 (128)
  {
    GJob jb = {XB1, WT + S, WT + 3 * S, WT + 5 * S, bh_bn + 512, bh_bl + 512, bh_bg + 512,
               XB0, 512, 512, 512, 3, 1, 3, 0};
    GJob jc = {XC1, WT + 7 * S, WT + 9 * S, WT + 11 * S, ch_bn + 512, ch_bl + 512, ch_bg + 512,
               XC0, 512, 512, 512, 3, 1, 3, 512};
    GJob js = jc; js.blk0 = SENT;
    mgemm3_k<<<640, 256, 0, stream>>>(jb, jc, js, 640, nullptr, nullptr, nullptr, nullptr);
  }
  // G3: EW gemm (512) + UHT gemm (128) + tscore tail (1024)
  {
    GJob je = {XB0, WT + 12 * S, nullptr, nullptr, m_bq, nullptr, nullptr,
               EW, 512, 512, 512, 3, 2, 1, 0};
    GJob ju = {XC0, WT + 13 * S, nullptr, nullptr, nullptr, nullptr, nullptr,
               UHT, 512, 512, 512, 3, 3, 1, 512};
    GJob js = ju; js.blk0 = SENT;
    mgemm3_k<<<1664, 256, 0, stream>>>(je, ju, js, 640, UHA, WQA, a_v, T);
  }

  mscore_k<<<512, 512, 0, stream>>>(EW, UHT, m_v, BSC);
  seg_k<<<dim3(402, 8), 256, 0, stream>>>(T, BSC, b_enc, SEG, SCO);
  final_k<<<8, 256, 0, stream>>>(SCO, SEG, out);
}